// Round 7
// baseline (1197.531 us; speedup 1.0000x reference)
//
#include <hip/hip_runtime.h>
#include <cstdint>
#include <cstddef>

typedef __attribute__((ext_vector_type(4))) int int32x4;
typedef __attribute__((ext_vector_type(16))) int int32x16;

#define DEVI __device__ __forceinline__

constexpr int M = 16384;
constexpr int N = 11008;
constexpr int K = 4096;
constexpr int BM = 256, BN = 256, BK = 64;   // BK in int8 elements (= bytes)
constexpr int NT_M = M / BM;                 // 64
constexpr int NT_N = N / BN;                 // 43
constexpr int NTILES = K / BK;               // 64
constexpr int NWG = NT_M * NT_N;             // 2752 = 8 * 344 (exact)
constexpr int TILE_BYTES = BM * BK;          // 16 KB per tensor per slot

DEVI void gload_lds16(const void* gsrc, void* ldst) {
  __builtin_amdgcn_global_load_lds(
      (const __attribute__((address_space(1))) unsigned int*)gsrc,
      (__attribute__((address_space(3))) unsigned int*)ldst,
      16, 0, 0);
}

// ---- weight repack: int32 (harness int convention) -> int8 ----
__global__ __launch_bounds__(256) void pack_w_kernel(const int* __restrict__ w32,
                                                     signed char* __restrict__ w8) {
  const int idx = blockIdx.x * 256 + threadIdx.x;
  const int total4 = N * K / 4;
  if (idx < total4) {
    const int4 v = ((const int4*)w32)[idx];
    ((int*)w8)[idx] = (v.x & 255) | ((v.y & 255) << 8) |
                      ((v.z & 255) << 16) | ((v.w & 255) << 24);
  }
}

// ---- per-row symmetric int8 quantization of X ----
__global__ __launch_bounds__(256) void quant_x_kernel(const float* __restrict__ x,
                                                      signed char* __restrict__ xq,
                                                      float* __restrict__ sx) {
  const int row = blockIdx.x;
  const int t = threadIdx.x;
  const float4* xr = (const float4*)(x + (size_t)row * K);
  float4 v[4];
  float amax = 0.f;
  #pragma unroll
  for (int c = 0; c < 4; ++c) {
    v[c] = xr[c * 256 + t];
    amax = fmaxf(amax, fmaxf(fmaxf(fabsf(v[c].x), fabsf(v[c].y)),
                             fmaxf(fabsf(v[c].z), fabsf(v[c].w))));
  }
  __shared__ float red[256];
  red[t] = amax;
  __syncthreads();
  #pragma unroll
  for (int s = 128; s >= 1; s >>= 1) {
    if (t < s) red[t] = fmaxf(red[t], red[t + s]);
    __syncthreads();
  }
  const float am = fmaxf(red[0], 1e-20f);
  const float inv = 127.f / am;
  if (t == 0) sx[row] = am * (1.f / 127.f);
  int* xq32 = (int*)(xq + (size_t)row * K);
  #pragma unroll
  for (int c = 0; c < 4; ++c) {
    int q0 = min(127, max(-127, __float2int_rn(v[c].x * inv)));
    int q1 = min(127, max(-127, __float2int_rn(v[c].y * inv)));
    int q2 = min(127, max(-127, __float2int_rn(v[c].z * inv)));
    int q3 = min(127, max(-127, __float2int_rn(v[c].w * inv)));
    xq32[c * 256 + t] = (q0 & 255) | ((q1 & 255) << 8) |
                        ((q2 & 255) << 16) | ((q3 & 255) << 24);
  }
}

// ---- 256x256 int8 GEMM, ring-4 LDS, 4 fine phases per K-tile (m201 port) ----
// Phase = {2-4 ds_read_b128 subtile || 1 gload_lds -> BAR -> lgkm(0) ->
//          setprio(1) + 4 MFMA (one C-quadrant) + setprio(0) -> BAR}.
// Quadrant = (i-half, k-step); B frags loaded at k-step phases, reused next.
// Counted vmcnt(8) once per tile (before P3's barrier) certifies tile t+1;
// epilogue drains 8 -> 4 -> 0. Ring invariant identical to round 6.
// LDS slot: A 16 KB k-plane-major (plane*4096 + row*16), B at +64 KB.
__global__ __launch_bounds__(512, 2) void gemm_i8_kernel(const signed char* __restrict__ aq,
                                                         const signed char* __restrict__ wq,
                                                         const float* __restrict__ sx,
                                                         const float* __restrict__ sw,
                                                         float* __restrict__ out) {
  extern __shared__ signed char smem[];            // 131072 B: 4 slots x 32 KB
  signed char* lsA = smem;                          // 4 slots x 16 KB (A)
  signed char* lsB = smem + 4 * TILE_BYTES;         // 4 slots x 16 KB (B)

  const int t = threadIdx.x;
  const int w = t >> 6;            // wave 0..7
  const int l = t & 63;

  // XCD swizzle (bijective: 2752 % 8 == 0), then nt-major tile order:
  // consecutive wg on an XCD share the same B panel (L2-resident, 1 MB).
  const int bid = blockIdx.x;
  const int wg = (bid & 7) * (NWG / 8) + (bid >> 3);
  const int mt = wg & 63;          // wg % 64  (fast axis: A panel)
  const int nt = wg >> 6;          // wg / 64  (slow axis: B panel)
  const int m0 = mt * BM, n0 = nt * BN;

  // Staging: waves 0..3 stage A, waves 4..7 stage B; 4 x 16B chunks/thread.
  const bool stA = (w < 4);
  const signed char* src[4];
  int loff[4];
  #pragma unroll
  for (int c = 0; c < 4; ++c) {
    const int q = (w & 3) * 4 + c;       // chunk id within tensor, 0..15
    const int row = (q & 3) * 64 + l;
    const int s = q >> 2;                // k-plane 0..3
    const signed char* base = stA ? (aq + (size_t)(m0 + row) * K)
                                  : (wq + (size_t)(n0 + row) * K);
    src[c] = base + s * 16;
    loff[c] = q * 1024;                  // wave-uniform dest; HW adds lane*16
  }

#define STG1(tile, c)                                                         \
  {                                                                           \
    signed char* lbase = (stA ? lsA : lsB) + ((tile) & 3) * TILE_BYTES;       \
    gload_lds16(src[c] + (tile) * BK, lbase + loff[c]);                       \
  }
#define STG_FULL(tile) STG1(tile, 0) STG1(tile, 1) STG1(tile, 2) STG1(tile, 3)

  // Wave output: 128x64 at (wm*128, wn*64); 4x2 frags of 32x32.
  const int wm = w >> 2, wn = w & 3;
  const int lk = l >> 5;           // 16B plane within k-step
  const int lr = l & 31;
  int aOff[4], bOff[2];
  #pragma unroll
  for (int i = 0; i < 4; ++i)
    aOff[i] = lk * 4096 + (wm * 128 + i * 32 + lr) * 16;
  #pragma unroll
  for (int j = 0; j < 2; ++j)
    bOff[j] = lk * 4096 + (wn * 64 + j * 32 + lr) * 16;

  int32x16 acc[4][2] = {};
  int32x4 b0[2], b1[2], aA[2], aB[2], aC[2], aD[2];

#define DSA2(tile, ks, ib, R)                                                 \
  {                                                                           \
    const signed char* pA = lsA + ((tile) & 3) * TILE_BYTES + (ks) * 8192;    \
    R[0] = *(const int32x4*)(pA + aOff[ib]);                                  \
    R[1] = *(const int32x4*)(pA + aOff[(ib) + 1]);                            \
  }
#define DSB2(tile, ks, R)                                                     \
  {                                                                           \
    const signed char* pB = lsB + ((tile) & 3) * TILE_BYTES + (ks) * 8192;    \
    R[0] = *(const int32x4*)(pB + bOff[0]);                                   \
    R[1] = *(const int32x4*)(pB + bOff[1]);                                   \
  }

#define LGKM0()                                          \
  asm volatile("s_waitcnt lgkmcnt(0)" ::: "memory");     \
  __builtin_amdgcn_sched_barrier(0);

#define MFMA4(A2, B2, ib)                                                     \
  __builtin_amdgcn_s_setprio(1);                                              \
  acc[ib][0] = __builtin_amdgcn_mfma_i32_32x32x32_i8(A2[0], B2[0],            \
                                                     acc[ib][0], 0, 0, 0);    \
  acc[ib][1] = __builtin_amdgcn_mfma_i32_32x32x32_i8(A2[0], B2[1],            \
                                                     acc[ib][1], 0, 0, 0);    \
  acc[(ib) + 1][0] = __builtin_amdgcn_mfma_i32_32x32x32_i8(A2[1], B2[0],      \
                                                     acc[(ib) + 1][0], 0, 0, 0);\
  acc[(ib) + 1][1] = __builtin_amdgcn_mfma_i32_32x32x32_i8(A2[1], B2[1],      \
                                                     acc[(ib) + 1][1], 0, 0, 0);\
  __builtin_amdgcn_s_setprio(0);

#define WAITV(n) asm volatile("s_waitcnt vmcnt(" #n ")" ::: "memory");
#define BAR() __builtin_amdgcn_s_barrier();

  // One K-tile = 4 fine phases. WV = tile-boundary vmcnt (before P3's BAR).
#define ITER(tt, WV)                                                          \
  /* P0: B(k0) + A01(k0) */                                                   \
  DSB2(tt, 0, b0) DSA2(tt, 0, 0, aA) STG1(tt + 3, 0)                          \
  BAR() LGKM0() MFMA4(aA, b0, 0) BAR()                                        \
  /* P1: A23(k0), B reused */                                                 \
  DSA2(tt, 0, 2, aB) STG1(tt + 3, 1)                                          \
  BAR() LGKM0() MFMA4(aB, b0, 2) BAR()                                        \
  /* P2: B(k1) + A01(k1) */                                                   \
  DSB2(tt, 1, b1) DSA2(tt, 1, 0, aC) STG1(tt + 3, 2)                          \
  BAR() LGKM0() MFMA4(aC, b1, 0) BAR()                                        \
  /* P3: A23(k1) + tile-boundary certification */                             \
  DSA2(tt, 1, 2, aD) STG1(tt + 3, 3)                                          \
  WV                                                                          \
  BAR() LGKM0() MFMA4(aD, b1, 2) BAR()

#define ITERN(tt, WV)                                                         \
  DSB2(tt, 0, b0) DSA2(tt, 0, 0, aA)                                          \
  BAR() LGKM0() MFMA4(aA, b0, 0) BAR()                                        \
  DSA2(tt, 0, 2, aB)                                                          \
  BAR() LGKM0() MFMA4(aB, b0, 2) BAR()                                        \
  DSB2(tt, 1, b1) DSA2(tt, 1, 0, aC)                                          \
  BAR() LGKM0() MFMA4(aC, b1, 0) BAR()                                        \
  DSA2(tt, 1, 2, aD)                                                          \
  WV                                                                          \
  BAR() LGKM0() MFMA4(aD, b1, 2) BAR()

  // Prologue: stage tiles 0..2 (12 loads); certify tile 0.
  STG_FULL(0) STG_FULL(1) STG_FULL(2)
  WAITV(8)
  BAR()

  #pragma unroll 4
  for (int tb = 0; tb < 60; ++tb) {
    ITER(tb, WAITV(8))
  }
  ITER(60, WAITV(8))       // stages tile 63 (last); certifies 61
  ITERN(61, WAITV(4))      // certifies 62
  ITERN(62, WAITV(0))      // certifies 63
  ITERN(63, )              // final tile

  // Epilogue: dequant + store.
  // 32x32 C/D map: col = lane&31, row = (r&3) + 8*(r>>2) + 4*(lane>>5).
  const int rbase = lk * 4;
  float swv[2];
  #pragma unroll
  for (int fj = 0; fj < 2; ++fj) swv[fj] = sw[n0 + wn * 64 + fj * 32 + lr];
  #pragma unroll
  for (int fi = 0; fi < 4; ++fi) {
    #pragma unroll
    for (int r = 0; r < 16; ++r) {
      const int row = (r & 3) + 8 * (r >> 2) + rbase;
      const int grow = m0 + wm * 128 + fi * 32 + row;
      const float sxv = sx[grow];
      float* orow = out + (size_t)grow * N + n0 + wn * 64 + lr;
      #pragma unroll
      for (int fj = 0; fj < 2; ++fj) {
        orow[fj * 32] = (float)acc[fi][fj][r] * sxv * swv[fj];
      }
    }
  }
}

extern "C" void kernel_launch(void* const* d_in, const int* in_sizes, int n_in,
                              void* d_out, int out_size, void* d_ws, size_t ws_size,
                              hipStream_t stream) {
  const float* x = (const float*)d_in[0];
  const int* w32 = (const int*)d_in[1];
  const float* wscale = (const float*)d_in[2];
  float* out = (float*)d_out;

  signed char* xq = (signed char*)d_ws;
  signed char* wq = xq + (size_t)M * K;
  float* sx = (float*)(wq + (size_t)N * K);

  pack_w_kernel<<<(N * K / 4 + 255) / 256, 256, 0, stream>>>(w32, wq);
  quant_x_kernel<<<M, 256, 0, stream>>>(x, xq, sx);
  gemm_i8_kernel<<<NWG, 512, 131072, stream>>>(xq, wq, sx, wscale, out);
}